// Round 7
// baseline (1325.247 us; speedup 1.0000x reference)
//
#include <hip/hip_runtime.h>

typedef __bf16 bf16_t;
typedef __bf16 bf16x8 __attribute__((ext_vector_type(8)));
typedef float f32x4 __attribute__((ext_vector_type(4)));

#define TSEQ 30
#define ISZ  100
#define HSZ  256
#define NB   5120        // LSTM batch
#define BATCH 512
#define G4   1024        // 4*H
#define XP   128         // padded x feature size
#define KP   384         // padded K = XP + HSZ
#define ROWB 768         // KP * 2 bytes per LDS act row
#define TILE 80          // batch cols per block (the W-volume lever: traffic = NB/TILE * W * T)
#define NF   5           // TILE/16 n-fragments

__device__ __forceinline__ float fsig(float x)  { return 1.0f / (1.0f + __expf(-x)); }
__device__ __forceinline__ float ftanh(float x) { return 2.0f / (1.0f + __expf(-2.0f * x)) - 1.0f; }

// ---- prep: weights -> MFMA-fragment layout, fold biases ------------------
// Wf[d][mf 0..63][ks 0..11][lane 0..63][e 0..7]; gate row r = h*4+gate
__global__ void prep_weights(const float* __restrict__ Wih_f, const float* __restrict__ Whh_f,
                             const float* __restrict__ bih_f, const float* __restrict__ bhh_f,
                             const float* __restrict__ Wih_b, const float* __restrict__ Whh_b,
                             const float* __restrict__ bih_b, const float* __restrict__ bhh_b,
                             bf16_t* __restrict__ Wf, float* __restrict__ bias)
{
    int idx = blockIdx.x * 256 + threadIdx.x;          // over 2*1024*384
    if (idx >= 2 * G4 * KP) return;
    int d = idx / (G4 * KP);
    int r = (idx / KP) % G4;
    int k = idx % KP;
    int h = r >> 2, gate = r & 3;
    int grow = gate * HSZ + h;
    const float* Wih = d ? Wih_b : Wih_f;
    const float* Whh = d ? Whh_b : Whh_f;
    float v;
    if (k < ISZ)       v = Wih[grow * ISZ + k];
    else if (k < XP)   v = 0.0f;
    else               v = Whh[grow * HSZ + (k - XP)];
    int mf = r >> 4, lr = r & 15;
    int ks = k >> 5, lq = (k >> 3) & 3, e = k & 7;
    size_t o = ((((size_t)d * 64 + mf) * 12 + ks) * 64 + lq * 16 + lr) * 8 + e;
    Wf[o] = (bf16_t)v;
    if (k == 0) {
        const float* bih = d ? bih_b : bih_f;
        const float* bhh = d ? bhh_b : bhh_f;
        bias[d * G4 + r] = bih[grow] + bhh[grow];
    }
}

// ---- prep: x -> per-(tile,t)-contiguous padded bf16 ----------------------
// xTp[tile64][t30][nl80][kp128]: each block-step reads one contiguous 20KB slab
__global__ void prep_x(const float* __restrict__ x, bf16_t* __restrict__ xTp)
{
    int idx = blockIdx.x * 256 + threadIdx.x;          // over 64*30*80*128
    if (idx >= TSEQ * NB * XP) return;
    int kp   = idx & 127;
    int nl   = (idx >> 7) % TILE;
    int t    = ((idx >> 7) / TILE) % TSEQ;
    int tile = idx / (128 * TILE * TSEQ);
    int gn   = tile * TILE + nl;
    float v = (kp < ISZ) ? x[(size_t)gn * (TSEQ * ISZ) + t * ISZ + kp] : 0.0f;
    xTp[idx] = (bf16_t)v;
}

// ---- prep: transpose W1 for coalesced head ------------------------------
__global__ void prep_w1t(const float* __restrict__ W1, float* __restrict__ W1T)
{
    int idx = blockIdx.x * 256 + threadIdx.x;          // over 2560*64
    if (idx >= 2560 * 64) return;
    int k = idx / 64, j = idx % 64;
    W1T[k * 64 + j] = W1[j * 2560 + k];
}

// ---- persistent LSTM: 128 blocks x 512 thr; block owns (dir, 80 cols) ----
// Wave w owns 8 mf (128 gate rows), processed in 2 groups of 4 so only
// acc[4][5]=80 AGPR live at once. c-state lives in LDS (cstL, same region
// doubles as final-h staging). Group-0 h held in 20 regs until barrier B.
__global__ __launch_bounds__(512, 1)
void lstm_persist(const bf16_t* __restrict__ Wf, const float* __restrict__ bias,
                  const bf16_t* __restrict__ xTp, const float* __restrict__ h0,
                  const float* __restrict__ c0, float* __restrict__ hfin)
{
    __shared__ __align__(16) unsigned char smem[4096 + TILE * ROWB + TILE * 257 * 4];
    float* biasL = (float*)smem;
    unsigned char* actL = smem + 4096;
    float* cstL = (float*)(smem + 4096 + TILE * ROWB);   // c-state; aliases hstage at end

    const int dir  = blockIdx.x & 1;
    const int tile = blockIdx.x >> 1;
    const int n0   = tile * TILE;
    const int tid  = threadIdx.x;
    const int wave = tid >> 6;                         // 0..7
    const int lane = tid & 63;
    const int lr   = lane & 15;
    const int lq   = lane >> 4;

    const bf16_t* xT_t = xTp + (size_t)tile * TSEQ * TILE * XP;
    const bf16_t* wbase = Wf + ((size_t)dir * 64 + wave * 8) * 12 * 512;

    // --- init: bias; h0 -> act (bf16 swizzled); c0 -> cstL (coalesced); x(t0) ---
    for (int i = tid; i < G4; i += 512) biasL[i] = bias[dir * G4 + i];
    for (int i = tid; i < TILE * HSZ; i += 512) {
        int n = i >> 8, h = i & 255;
        float v = h0[((size_t)dir * NB + n0 + n) * HSZ + h];
        *(bf16_t*)(actL + n * ROWB + ((256 + 2 * h) ^ ((n & 7) << 4))) = (bf16_t)v;
        cstL[n * 257 + h] = c0[((size_t)dir * NB + n0 + n) * HSZ + h];
    }
    {
        int tx0 = dir == 0 ? 0 : TSEQ - 1;
        for (int i = tid; i < TILE * 16; i += 512) {
            int n = i >> 4, ck = i & 15;
            uint4 v = *(const uint4*)(xT_t + ((size_t)tx0 * TILE + n) * XP + ck * 8);
            *(uint4*)(actL + n * ROWB + ((ck * 16) ^ ((n & 7) << 4))) = v;
        }
    }

#pragma unroll 1
    for (int t = 0; t < TSEQ; ++t) {
        const int last = (t == TSEQ - 1);
        __syncthreads();                               // barrier A: act ready

        float hn0[4][NF];                              // group-0 h, written after barrier B

#pragma unroll
        for (int g = 0; g < 2; ++g) {
            f32x4 acc[4][NF] = {};
#pragma unroll
            for (int ks = 0; ks < 12; ++ks) {
                bf16x8 b[NF];
#pragma unroll
                for (int nf = 0; nf < NF; ++nf) {
                    int row = nf * 16 + lr;
                    b[nf] = *(const bf16x8*)(actL + row * ROWB + ((ks * 64 + lq * 16) ^ ((row & 7) << 4)));
                }
                bf16x8 aC[4];
#pragma unroll
                for (int m = 0; m < 4; ++m)
                    aC[m] = *(const bf16x8*)(wbase + (((size_t)(g * 4 + m) * 12 + ks) * 64 + lane) * 8);
#pragma unroll
                for (int m = 0; m < 4; ++m)
#pragma unroll
                    for (int nf = 0; nf < NF; ++nf)
                        acc[m][nf] = __builtin_amdgcn_mfma_f32_16x16x32_bf16(aC[m], b[nf], acc[m][nf], 0, 0, 0);
            }

            if (g == 0) {
                // group-0 gates now (act untouched); h kept in regs until barrier B
#pragma unroll
                for (int m = 0; m < 4; ++m) {
                    int h = wave * 32 + m * 4 + lq;
                    float4 bb = *(const float4*)(biasL + 4 * h);
#pragma unroll
                    for (int nf = 0; nf < NF; ++nf) {
                        int n = nf * 16 + lr;
                        f32x4 gg = acc[m][nf];
                        float gi = fsig(gg[0] + bb.x);
                        float gf = fsig(gg[1] + bb.y);
                        float gz = ftanh(gg[2] + bb.z);
                        float go = fsig(gg[3] + bb.w);
                        float cn = gf * cstL[n * 257 + h] + gi * gz;
                        cstL[n * 257 + h] = cn;
                        float hn = go * ftanh(cn);
                        if (last) cstL[n * 257 + h] = hn;   // hstage alias (same-thread slot)
                        else      hn0[m][nf] = hn;
                    }
                }
            } else {
                __syncthreads();                       // barrier B: all act reads done
                // group-1 gates + direct act writes
#pragma unroll
                for (int m = 0; m < 4; ++m) {
                    int h = wave * 32 + 16 + m * 4 + lq;
                    float4 bb = *(const float4*)(biasL + 4 * h);
#pragma unroll
                    for (int nf = 0; nf < NF; ++nf) {
                        int n = nf * 16 + lr;
                        f32x4 gg = acc[m][nf];
                        float gi = fsig(gg[0] + bb.x);
                        float gf = fsig(gg[1] + bb.y);
                        float gz = ftanh(gg[2] + bb.z);
                        float go = fsig(gg[3] + bb.w);
                        float cn = gf * cstL[n * 257 + h] + gi * gz;
                        cstL[n * 257 + h] = cn;
                        float hn = go * ftanh(cn);
                        if (last) cstL[n * 257 + h] = hn;
                        else
                            *(bf16_t*)(actL + n * ROWB + ((256 + 2 * h) ^ ((n & 7) << 4))) = (bf16_t)hn;
                    }
                }
            }
        }

        if (!last) {
            // group-0 h -> act
#pragma unroll
            for (int m = 0; m < 4; ++m) {
                int h = wave * 32 + m * 4 + lq;
#pragma unroll
                for (int nf = 0; nf < NF; ++nf) {
                    int n = nf * 16 + lr;
                    *(bf16_t*)(actL + n * ROWB + ((256 + 2 * h) ^ ((n & 7) << 4))) = (bf16_t)hn0[m][nf];
                }
            }
            // stage x(t+1): one contiguous 20KB slab
            int tx = dir == 0 ? t + 1 : TSEQ - 2 - t;
            for (int i = tid; i < TILE * 16; i += 512) {
                int n = i >> 4, ck = i & 15;
                uint4 v = *(const uint4*)(xT_t + ((size_t)tx * TILE + n) * XP + ck * 8);
                *(uint4*)(actL + n * ROWB + ((ck * 16) ^ ((n & 7) << 4))) = v;
            }
        }
    }
    __syncthreads();
    // --- coalesced hfin write from cstL (= hstage) ---
    for (int i = tid; i < TILE * HSZ; i += 512) {
        int n = i >> 8, h = i & 255;
        hfin[((size_t)dir * NB + n0 + n) * HSZ + h] = cstL[n * 257 + h];
    }
}

// ---- head: x_fea assembly + Linear(2560,64) + Linear(64,5) + softmax ----
__global__ __launch_bounds__(256)
void head_kernel(const float* __restrict__ hfin, const float* __restrict__ W1T,
                 const float* __restrict__ b1, const float* __restrict__ W2,
                 const float* __restrict__ b2, float* __restrict__ out)
{
    __shared__ float flat_s[2560];
    __shared__ float partial[4][64];
    __shared__ float zs[64];
    __shared__ float ls[5];
    __shared__ float es[5];
    int b = blockIdx.x, tid = threadIdx.x;
    const float* hF = hfin;
    const float* hB = hfin + (size_t)NB * HSZ;
    float* xfea = out + BATCH * 5 + (size_t)b * 2560;

    for (int j = tid; j < 2560; j += 256) {
        int s = j >> 8, c = j & 255;
        int n = b * 10 + s;
        float v = (c < 128) ? hF[(size_t)n * HSZ + c] : hB[(size_t)n * HSZ + c];
        flat_s[j] = v;
        xfea[j] = v;
    }
    __syncthreads();
    int j = tid & 63, q = tid >> 6;
    float sum = 0.0f;
    for (int k = q * 640; k < (q + 1) * 640; ++k) sum += flat_s[k] * W1T[k * 64 + j];
    partial[q][j] = sum;
    __syncthreads();
    if (tid < 64) zs[tid] = partial[0][tid] + partial[1][tid] + partial[2][tid] + partial[3][tid] + b1[tid];
    __syncthreads();
    if (tid < 5) {
        float l = b2[tid];
        for (int k = 0; k < 64; ++k) l += zs[k] * W2[tid * 64 + k];
        ls[tid] = l;
    }
    __syncthreads();
    if (tid < 5) {
        float m = ls[0];
        for (int k = 1; k < 5; ++k) m = fmaxf(m, ls[k]);
        es[tid] = __expf(ls[tid] - m);
    }
    __syncthreads();
    if (tid < 5) {
        float s5 = es[0] + es[1] + es[2] + es[3] + es[4];
        out[b * 5 + tid] = es[tid] / s5;
    }
}

extern "C" void kernel_launch(void* const* d_in, const int* in_sizes, int n_in,
                              void* d_out, int out_size, void* d_ws, size_t ws_size,
                              hipStream_t stream) {
    const float* x     = (const float*)d_in[0];
    const float* h0    = (const float*)d_in[1];
    const float* c0    = (const float*)d_in[2];
    const float* Wih_f = (const float*)d_in[3];
    const float* Whh_f = (const float*)d_in[4];
    const float* bih_f = (const float*)d_in[5];
    const float* bhh_f = (const float*)d_in[6];
    const float* Wih_b = (const float*)d_in[7];
    const float* Whh_b = (const float*)d_in[8];
    const float* bih_b = (const float*)d_in[9];
    const float* bhh_b = (const float*)d_in[10];
    const float* W1    = (const float*)d_in[11];
    const float* b1    = (const float*)d_in[12];
    const float* W2    = (const float*)d_in[13];
    const float* b2    = (const float*)d_in[14];
    float* out = (float*)d_out;

    uintptr_t ws = (uintptr_t)d_ws;
    bf16_t* Wf   = (bf16_t*)(ws);                      // 2*1024*384*2   = 1,572,864
    float*  bias = (float*)(ws + 1572864);             // 2*1024*4       = 8,192
    bf16_t* xTp  = (bf16_t*)(ws + 1581056);            // 30*5120*128*2  = 39,321,600
    float*  hfin = (float*)(ws + 40902656);            // 2*5120*256*4   = 10,485,760
    float*  W1T  = (float*)(ws + 51388416);            // 2560*64*4      = 655,360

    prep_weights<<<(2 * G4 * KP + 255) / 256, 256, 0, stream>>>(
        Wih_f, Whh_f, bih_f, bhh_f, Wih_b, Whh_b, bih_b, bhh_b, Wf, bias);
    prep_x<<<(TSEQ * NB * XP + 255) / 256, 256, 0, stream>>>(x, xTp);
    prep_w1t<<<(2560 * 64 + 255) / 256, 256, 0, stream>>>(W1, W1T);

    lstm_persist<<<128, 512, 0, stream>>>(Wf, bias, xTp, h0, c0, hfin);
    head_kernel<<<BATCH, 256, 0, stream>>>(hfin, W1T, b1, W2, b2, out);
}